// Round 2
// baseline (757.447 us; speedup 1.0000x reference)
//
#include <hip/hip_runtime.h>
#include <hip/hip_bf16.h>

// MoE: E=8, K=2, D=1024, F=4096, T=4096 tokens. fp32 in/out, bf16 MFMA inside.
// R1: split-K=4 GEMM2 (576->2304 blocks), sigmoid-form gelu, 64x64 float4 transpose.

#define T_TOK 4096
#define D_DIM 1024
#define F_DIM 4096
#define E_NUM 8
#define CAP   9216   // 72 tiles * 128

typedef short short8 __attribute__((ext_vector_type(8)));
typedef float f32x4  __attribute__((ext_vector_type(4)));

__device__ __forceinline__ void async_ld16(const void* g, void* l) {
  __builtin_amdgcn_global_load_lds(
      (const __attribute__((address_space(1))) char*)g,
      (__attribute__((address_space(3))) char*)l,
      16, 0, 0);
}

// ---------------- transpose + fp32->bf16 cast:  in [E][R][C] -> out [E][C][R]
// 64x64 tile, float4 loads, ushort4 stores. LDS 64x65 fp32: both phases are
// 2-way bank aliases only (free on CDNA4 — m136).
__global__ void transpose_cast(const float* __restrict__ in, __hip_bfloat16* __restrict__ out,
                               int R, int C) {
  __shared__ float t[64][65];
  const int ex = blockIdx.z;
  in  += (size_t)ex * R * C;
  out += (size_t)ex * R * C;
  const int r0 = blockIdx.y * 64, c0 = blockIdx.x * 64;
  const int tx = threadIdx.x & 15;        // 16 x float4 across 64 cols
  const int ty = threadIdx.x >> 4;        // 16 rows per pass
#pragma unroll
  for (int i = 0; i < 4; ++i) {
    const int r = ty + i * 16;
    const float4 v = *(const float4*)(in + (size_t)(r0 + r) * C + c0 + tx * 4);
    t[r][tx * 4 + 0] = v.x; t[r][tx * 4 + 1] = v.y;
    t[r][tx * 4 + 2] = v.z; t[r][tx * 4 + 3] = v.w;
  }
  __syncthreads();
#pragma unroll
  for (int i = 0; i < 4; ++i) {
    const int c = ty + i * 16;            // col in tile -> output row
    union { __hip_bfloat16 h[4]; ushort4 u; } pk;
#pragma unroll
    for (int k = 0; k < 4; ++k) pk.h[k] = __float2bfloat16(t[tx * 4 + k][c]);
    *(ushort4*)(out + (size_t)(c0 + c) * R + r0 + tx * 4) = pk.u;
  }
}

// ---------------- router: logits (fp32 out), softmax, top-2, slot assignment
__global__ void router_kernel(const float* __restrict__ x, const float* __restrict__ gw,
                              float* __restrict__ logits, int* __restrict__ counts,
                              int* __restrict__ tk_e, int* __restrict__ tk_pos,
                              float* __restrict__ tk_w) {
  const int lane = threadIdx.x & 63;
  const int t = blockIdx.x * 4 + (threadIdx.x >> 6);
  const float* xr = x + (size_t)t * D_DIM;
  float a[8] = {0.f, 0.f, 0.f, 0.f, 0.f, 0.f, 0.f, 0.f};
  for (int it = 0; it < D_DIM / 64; ++it) {
    const int d = lane + it * 64;
    const float xv = xr[d];
    const float4 g0 = *(const float4*)(gw + d * 8);
    const float4 g1 = *(const float4*)(gw + d * 8 + 4);
    a[0] += xv * g0.x; a[1] += xv * g0.y; a[2] += xv * g0.z; a[3] += xv * g0.w;
    a[4] += xv * g1.x; a[5] += xv * g1.y; a[6] += xv * g1.z; a[7] += xv * g1.w;
  }
#pragma unroll
  for (int off = 32; off > 0; off >>= 1)
#pragma unroll
    for (int e = 0; e < 8; ++e) a[e] += __shfl_down(a[e], off);
  if (lane == 0) {
    float mx = a[0];
#pragma unroll
    for (int e = 1; e < 8; ++e) mx = fmaxf(mx, a[e]);
    float p[8];
#pragma unroll
    for (int e = 0; e < 8; ++e) p[e] = __expf(a[e] - mx);
    int i1 = 0;
#pragma unroll
    for (int e = 1; e < 8; ++e) if (p[e] > p[i1]) i1 = e;   // strict >: lowest index on tie (lax.top_k)
    int i2 = (i1 == 0) ? 1 : 0;
#pragma unroll
    for (int e = 0; e < 8; ++e) if (e != i1 && p[e] > p[i2]) i2 = e;
    const float inv = 1.f / (p[i1] + p[i2]);
#pragma unroll
    for (int e = 0; e < 8; ++e) logits[(size_t)t * 8 + e] = a[e];
    const int p1 = atomicAdd(counts + i1, 1);
    const int p2 = atomicAdd(counts + i2, 1);
    tk_e[t * 2]     = i1; tk_pos[t * 2]     = p1; tk_w[t * 2]     = p[i1] * inv;
    tk_e[t * 2 + 1] = i2; tk_pos[t * 2 + 1] = p2; tk_w[t * 2 + 1] = p[i2] * inv;
  }
}

// ---------------- bases: 128-aligned prefix sum so GEMM tiles never straddle experts
__global__ void prefix_kernel(const int* __restrict__ counts, int* __restrict__ bases) {
  if (threadIdx.x == 0 && blockIdx.x == 0) {
    int b = 0;
    for (int e = 0; e < 8; ++e) { bases[e] = b; b += (counts[e] + 127) & ~127; }
    bases[8] = b;
  }
}

// ---------------- gather token rows into Xg (bf16), fill slot maps
__global__ void gather_kernel(const float* __restrict__ x, const int* __restrict__ bases,
                              const int* __restrict__ tk_e, const int* __restrict__ tk_pos,
                              const float* __restrict__ tk_w,
                              __hip_bfloat16* __restrict__ Xg,
                              int* __restrict__ slot_token, float* __restrict__ slot_weight) {
  const int b = blockIdx.x;        // (token, k) pair
  const int t = b >> 1;
  const int slot = bases[tk_e[b]] + tk_pos[b];
  if (threadIdx.x == 0) { slot_token[slot] = t; slot_weight[slot] = tk_w[b]; }
  const float4 v = ((const float4*)(x + (size_t)t * D_DIM))[threadIdx.x];
  union { __hip_bfloat16 h[4]; ushort4 u; } pk;
  pk.h[0] = __float2bfloat16(v.x);
  pk.h[1] = __float2bfloat16(v.y);
  pk.h[2] = __float2bfloat16(v.z);
  pk.h[3] = __float2bfloat16(v.w);
  ((ushort4*)(Xg + (size_t)slot * D_DIM))[threadIdx.x] = pk.u;
}

// ---------------- grouped GEMM, m97 structure: 128x128 tile, BK=32, 4 waves x (4x4) 16x16x32 MFMA
// A: [cap][K] bf16 row-major.  Bt: [E][N][K] bf16 (K contiguous).
// IS_FC: out = gelu_new(A@B + bias) -> Hout bf16.  (KSPLIT must be 1)
// else:  KSPLIT-way split-K over blockIdx.z; scatter atomicAdd((A@B + bias?) * w) into out,
//        bias added only by the z==0 chunk; padded slots masked.
template <int N, int K, int KSPLIT, bool IS_FC>
__global__ __launch_bounds__(256, 2) void moe_gemm(
    const __hip_bfloat16* __restrict__ A, const __hip_bfloat16* __restrict__ Bt,
    const float* __restrict__ bias, const int* __restrict__ counts,
    const int* __restrict__ bases, __hip_bfloat16* __restrict__ Hout,
    const int* __restrict__ slot_token, const float* __restrict__ slot_weight,
    float* __restrict__ out) {
  __shared__ __align__(16) __hip_bfloat16 As[128 * 32];
  __shared__ __align__(16) __hip_bfloat16 Bs[128 * 32];

  const int m0 = blockIdx.y * 128;
  const int total = bases[8];
  if (m0 >= total) return;
  int e = 0;
#pragma unroll
  for (int i = 1; i < 8; ++i) e = (m0 >= bases[i]) ? i : e;
  const int n0 = blockIdx.x * 128;
  constexpr int KC = K / KSPLIT;
  const int kbase = blockIdx.z * KC;

  const __hip_bfloat16* Ab = A + (size_t)m0 * K + kbase;
  const __hip_bfloat16* Bb = Bt + ((size_t)e * N + n0) * K + kbase;

  const int tid = threadIdx.x;
  const int lane = tid & 63;
  const int wave = tid >> 6;
  const int wm = (wave >> 1) * 64;
  const int wn = (wave & 1) * 64;
  const int lr = lane & 15;
  const int quad = lane >> 4;

  f32x4 acc[4][4] = {};

  // staging: 512 x 16B chunks per tile; thread covers chunks tid and tid+256.
  // LDS dest = wave-uniform base + lane*16 (global_load_lds constraint holds).
  const int c0 = tid, c1 = tid + 256;
  const int ar0 = c0 >> 2, ac0 = (c0 & 3) * 8;
  const int ar1 = c1 >> 2, ac1 = (c1 & 3) * 8;

  for (int k0 = 0; k0 < KC; k0 += 32) {
    async_ld16(Ab + (size_t)ar0 * K + k0 + ac0, As + c0 * 8);
    async_ld16(Ab + (size_t)ar1 * K + k0 + ac1, As + c1 * 8);
    async_ld16(Bb + (size_t)ar0 * K + k0 + ac0, Bs + c0 * 8);
    async_ld16(Bb + (size_t)ar1 * K + k0 + ac1, Bs + c1 * 8);
    __syncthreads();

    short8 af[4], bfr[4];
#pragma unroll
    for (int i = 0; i < 4; ++i)
      af[i] = *(const short8*)(As + (wm + i * 16 + lr) * 32 + quad * 8);
#pragma unroll
    for (int j = 0; j < 4; ++j)
      bfr[j] = *(const short8*)(Bs + (wn + j * 16 + lr) * 32 + quad * 8);
#pragma unroll
    for (int i = 0; i < 4; ++i)
#pragma unroll
      for (int j = 0; j < 4; ++j)
        acc[i][j] = __builtin_amdgcn_mfma_f32_16x16x32_bf16(af[i], bfr[j], acc[i][j], 0, 0, 0);
    __syncthreads();
  }

  // C/D layout (verified m89/m91): col = lane&15, row = quad*4 + reg
  if (IS_FC) {
#pragma unroll
    for (int j = 0; j < 4; ++j) {
      const int nc = n0 + wn + j * 16 + lr;
      const float bv = bias[(size_t)e * N + nc];
#pragma unroll
      for (int i = 0; i < 4; ++i) {
#pragma unroll
        for (int r = 0; r < 4; ++r) {
          const int row = m0 + wm + i * 16 + quad * 4 + r;
          const float v = acc[i][j][r] + bv;
          // gelu_new(v) = v * sigmoid(2c(v + 0.044715 v^3)), c = 0.79788456
          const float u2 = 1.5957691216057308f * (v + 0.044715f * v * v * v);
          const float g = v / (1.0f + __expf(-u2));
          Hout[(size_t)row * N + nc] = __float2bfloat16(g);
        }
      }
    }
  } else {
    const int base_e = bases[e];
    const int cnt = counts[e];
    const float bscale = (blockIdx.z == 0) ? 1.0f : 0.0f;
#pragma unroll
    for (int i = 0; i < 4; ++i) {
#pragma unroll
      for (int r = 0; r < 4; ++r) {
        const int row = m0 + wm + i * 16 + quad * 4 + r;
        if (row - base_e < cnt) {   // mask padded slots (poison garbage)
          const float w = slot_weight[row];
          const int t = slot_token[row];
          float* orow = out + (size_t)t * D_DIM;
#pragma unroll
          for (int j = 0; j < 4; ++j) {
            const int nc = n0 + wn + j * 16 + lr;
            atomicAdd(orow + nc, (acc[i][j][r] + bscale * bias[(size_t)e * N + nc]) * w);
          }
        }
      }
    }
  }
}

extern "C" void kernel_launch(void* const* d_in, const int* in_sizes, int n_in,
                              void* d_out, int out_size, void* d_ws, size_t ws_size,
                              hipStream_t stream) {
  const float* x      = (const float*)d_in[0];
  const float* gate_w = (const float*)d_in[1];
  const float* fc_w   = (const float*)d_in[2];
  const float* fc_b   = (const float*)d_in[3];
  const float* proj_w = (const float*)d_in[4];
  const float* proj_b = (const float*)d_in[5];
  float* out = (float*)d_out;
  float* logits = out + (size_t)T_TOK * D_DIM;

  char* ws = (char*)d_ws;
  __hip_bfloat16* fcT   = (__hip_bfloat16*)(ws);
  __hip_bfloat16* projT = (__hip_bfloat16*)(ws + 67108864LL);
  __hip_bfloat16* Xg    = (__hip_bfloat16*)(ws + 134217728LL);
  __hip_bfloat16* Hg    = (__hip_bfloat16*)(ws + 153092096LL);
  int* meta = (int*)(ws + 228589568LL);
  int*   counts      = meta;             // 8
  int*   bases       = meta + 8;         // 9
  int*   tk_e        = meta + 20;        // 8192
  int*   tk_pos      = tk_e + 8192;      // 8192
  float* tk_w        = (float*)(tk_pos + 8192);       // 8192
  int*   slot_token  = (int*)(tk_w + 8192);           // 9216
  float* slot_weight = (float*)(slot_token + CAP);    // 9216

  hipMemsetAsync(d_out, 0, (size_t)out_size * sizeof(float), stream);
  hipMemsetAsync(counts, 0, 8 * sizeof(int), stream);

  // weights: [K][N] fp32 -> [N][K] bf16
  transpose_cast<<<dim3(F_DIM / 64, D_DIM / 64, E_NUM), 256, 0, stream>>>(fc_w, fcT, D_DIM, F_DIM);
  transpose_cast<<<dim3(D_DIM / 64, F_DIM / 64, E_NUM), 256, 0, stream>>>(proj_w, projT, F_DIM, D_DIM);

  router_kernel<<<T_TOK / 4, 256, 0, stream>>>(x, gate_w, logits, counts, tk_e, tk_pos, tk_w);
  prefix_kernel<<<1, 64, 0, stream>>>(counts, bases);
  gather_kernel<<<T_TOK * 2, 256, 0, stream>>>(x, bases, tk_e, tk_pos, tk_w, Xg,
                                               slot_token, slot_weight);

  moe_gemm<F_DIM, D_DIM, 1, true><<<dim3(F_DIM / 128, CAP / 128, 1), 256, 0, stream>>>(
      Xg, fcT, fc_b, counts, bases, Hg, nullptr, nullptr, nullptr);
  moe_gemm<D_DIM, F_DIM, 4, false><<<dim3(D_DIM / 128, CAP / 128, 4), 256, 0, stream>>>(
      Hg, projT, proj_b, counts, bases, nullptr, slot_token, slot_weight, out);
}

// Round 3
// 695.967 us; speedup vs baseline: 1.0883x; 1.0883x over previous
//
#include <hip/hip_runtime.h>
#include <hip/hip_bf16.h>

// MoE: E=8, K=2, D=1024, F=4096, T=4096 tokens. fp32 in/out, bf16 MFMA inside.
// R2: GEMM2 atomics -> dense per-slot fp32 stores + combine kernel; 128x64 tiles
//     for GEMM2 (1152 blocks, no split-K); dropped d_out memset.
// ws layout (bytes):
//   [0,          64MB)  fcT   bf16 [8][4096][1024]  -- ALIASED by P after GEMM1
//   [0,       37.75MB)  P     fp32 [9216][1024]      (GEMM2 dense output; fcT dead by then)
//   [64MB,      128MB)  projT bf16 [8][1024][4096]
//   [128MB, +18.0MB )   Xg    bf16 [9216][1024]
//   [146MB, +75.5MB )   Hg    bf16 [9216][4096]
//   [~218MB, meta]      counts[8], bases[9], tk_e/tk_pos/tk_w[8192], slot_weight[9216]

#define T_TOK 4096
#define D_DIM 1024
#define F_DIM 4096
#define E_NUM 8
#define CAP   9216   // 72 tiles * 128

typedef short short8 __attribute__((ext_vector_type(8)));
typedef float f32x4  __attribute__((ext_vector_type(4)));

__device__ __forceinline__ void async_ld16(const void* g, void* l) {
  __builtin_amdgcn_global_load_lds(
      (const __attribute__((address_space(1))) char*)g,
      (__attribute__((address_space(3))) char*)l,
      16, 0, 0);
}

// ---------------- transpose + fp32->bf16 cast:  in [E][R][C] -> out [E][C][R]
__global__ void transpose_cast(const float* __restrict__ in, __hip_bfloat16* __restrict__ out,
                               int R, int C) {
  __shared__ float t[64][65];
  const int ex = blockIdx.z;
  in  += (size_t)ex * R * C;
  out += (size_t)ex * R * C;
  const int r0 = blockIdx.y * 64, c0 = blockIdx.x * 64;
  const int tx = threadIdx.x & 15;        // 16 x float4 across 64 cols
  const int ty = threadIdx.x >> 4;        // 16 rows per pass
#pragma unroll
  for (int i = 0; i < 4; ++i) {
    const int r = ty + i * 16;
    const float4 v = *(const float4*)(in + (size_t)(r0 + r) * C + c0 + tx * 4);
    t[r][tx * 4 + 0] = v.x; t[r][tx * 4 + 1] = v.y;
    t[r][tx * 4 + 2] = v.z; t[r][tx * 4 + 3] = v.w;
  }
  __syncthreads();
#pragma unroll
  for (int i = 0; i < 4; ++i) {
    const int c = ty + i * 16;            // col in tile -> output row
    union { __hip_bfloat16 h[4]; ushort4 u; } pk;
#pragma unroll
    for (int k = 0; k < 4; ++k) pk.h[k] = __float2bfloat16(t[tx * 4 + k][c]);
    *(ushort4*)(out + (size_t)(c0 + c) * R + r0 + tx * 4) = pk.u;
  }
}

// ---------------- router: logits (fp32 out), softmax, top-2, slot assignment
__global__ void router_kernel(const float* __restrict__ x, const float* __restrict__ gw,
                              float* __restrict__ logits, int* __restrict__ counts,
                              int* __restrict__ tk_e, int* __restrict__ tk_pos,
                              float* __restrict__ tk_w) {
  const int lane = threadIdx.x & 63;
  const int t = blockIdx.x * 4 + (threadIdx.x >> 6);
  const float* xr = x + (size_t)t * D_DIM;
  float a[8] = {0.f, 0.f, 0.f, 0.f, 0.f, 0.f, 0.f, 0.f};
  for (int it = 0; it < D_DIM / 64; ++it) {
    const int d = lane + it * 64;
    const float xv = xr[d];
    const float4 g0 = *(const float4*)(gw + d * 8);
    const float4 g1 = *(const float4*)(gw + d * 8 + 4);
    a[0] += xv * g0.x; a[1] += xv * g0.y; a[2] += xv * g0.z; a[3] += xv * g0.w;
    a[4] += xv * g1.x; a[5] += xv * g1.y; a[6] += xv * g1.z; a[7] += xv * g1.w;
  }
#pragma unroll
  for (int off = 32; off > 0; off >>= 1)
#pragma unroll
    for (int e = 0; e < 8; ++e) a[e] += __shfl_down(a[e], off);
  if (lane == 0) {
    float mx = a[0];
#pragma unroll
    for (int e = 1; e < 8; ++e) mx = fmaxf(mx, a[e]);
    float p[8];
#pragma unroll
    for (int e = 0; e < 8; ++e) p[e] = __expf(a[e] - mx);
    int i1 = 0;
#pragma unroll
    for (int e = 1; e < 8; ++e) if (p[e] > p[i1]) i1 = e;   // strict >: lowest index on tie (lax.top_k)
    int i2 = (i1 == 0) ? 1 : 0;
#pragma unroll
    for (int e = 0; e < 8; ++e) if (e != i1 && p[e] > p[i2]) i2 = e;
    const float inv = 1.f / (p[i1] + p[i2]);
#pragma unroll
    for (int e = 0; e < 8; ++e) logits[(size_t)t * 8 + e] = a[e];
    const int p1 = atomicAdd(counts + i1, 1);
    const int p2 = atomicAdd(counts + i2, 1);
    tk_e[t * 2]     = i1; tk_pos[t * 2]     = p1; tk_w[t * 2]     = p[i1] * inv;
    tk_e[t * 2 + 1] = i2; tk_pos[t * 2 + 1] = p2; tk_w[t * 2 + 1] = p[i2] * inv;
  }
}

// ---------------- bases: 128-aligned prefix sum so GEMM tiles never straddle experts
__global__ void prefix_kernel(const int* __restrict__ counts, int* __restrict__ bases) {
  if (threadIdx.x == 0 && blockIdx.x == 0) {
    int b = 0;
    for (int e = 0; e < 8; ++e) { bases[e] = b; b += (counts[e] + 127) & ~127; }
    bases[8] = b;
  }
}

// ---------------- gather token rows into Xg (bf16), fill slot weights
__global__ void gather_kernel(const float* __restrict__ x, const int* __restrict__ bases,
                              const int* __restrict__ tk_e, const int* __restrict__ tk_pos,
                              const float* __restrict__ tk_w,
                              __hip_bfloat16* __restrict__ Xg,
                              float* __restrict__ slot_weight) {
  const int b = blockIdx.x;        // (token, k) pair
  const int t = b >> 1;
  const int slot = bases[tk_e[b]] + tk_pos[b];
  if (threadIdx.x == 0) slot_weight[slot] = tk_w[b];
  const float4 v = ((const float4*)(x + (size_t)t * D_DIM))[threadIdx.x];
  union { __hip_bfloat16 h[4]; ushort4 u; } pk;
  pk.h[0] = __float2bfloat16(v.x);
  pk.h[1] = __float2bfloat16(v.y);
  pk.h[2] = __float2bfloat16(v.z);
  pk.h[3] = __float2bfloat16(v.w);
  ((ushort4*)(Xg + (size_t)slot * D_DIM))[threadIdx.x] = pk.u;
}

// ---------------- combine: out[t] = P[slot1(t)] + P[slot2(t)]  (weights/bias already applied)
__global__ void combine_kernel(const float* __restrict__ P, const int* __restrict__ bases,
                               const int* __restrict__ tk_e, const int* __restrict__ tk_pos,
                               float* __restrict__ out) {
  const int t = blockIdx.x;
  const int s1 = bases[tk_e[2 * t]]     + tk_pos[2 * t];
  const int s2 = bases[tk_e[2 * t + 1]] + tk_pos[2 * t + 1];
  const int d = threadIdx.x * 4;
  const float4 a = *(const float4*)(P + (size_t)s1 * D_DIM + d);
  const float4 b = *(const float4*)(P + (size_t)s2 * D_DIM + d);
  float4 o; o.x = a.x + b.x; o.y = a.y + b.y; o.z = a.z + b.z; o.w = a.w + b.w;
  *(float4*)(out + (size_t)t * D_DIM + d) = o;
}

// ---------------- grouped GEMM, m97 structure: 128(M)xBN(N) tile, BK=32,
// 4 waves of 16x16x32 MFMA. A: [cap][K] bf16 row-major. Bt: [E][N][K] bf16.
// IS_FC: Hout = gelu_new(A@B + bias) bf16.
// else:  Pout[row][:] = (A@B + bias) * slot_weight[row], dense fp32, padded rows skipped.
template <int N, int K, int BN, bool IS_FC>
__global__ __launch_bounds__(256, 2) void moe_gemm(
    const __hip_bfloat16* __restrict__ A, const __hip_bfloat16* __restrict__ Bt,
    const float* __restrict__ bias, const int* __restrict__ counts,
    const int* __restrict__ bases, __hip_bfloat16* __restrict__ Hout,
    const float* __restrict__ slot_weight, float* __restrict__ Pout) {
  __shared__ __align__(16) __hip_bfloat16 As[128 * 32];
  __shared__ __align__(16) __hip_bfloat16 Bs[BN * 32];

  const int m0 = blockIdx.y * 128;
  if (m0 >= bases[8]) return;
  int e = 0;
#pragma unroll
  for (int i = 1; i < 8; ++i) e = (m0 >= bases[i]) ? i : e;
  const int n0 = blockIdx.x * BN;

  const __hip_bfloat16* Ab = A + (size_t)m0 * K;
  const __hip_bfloat16* Bb = Bt + ((size_t)e * N + n0) * K;

  const int tid = threadIdx.x;
  const int lane = tid & 63;
  const int wave = tid >> 6;
  const int wm = (wave >> 1) * 64;
  const int wn = (wave & 1) * (BN / 2);
  constexpr int MJ = BN / 32;           // 16-col fragments per wave (4 or 2)
  const int lr = lane & 15;
  const int quad = lane >> 4;

  f32x4 acc[4][MJ] = {};

  // staging: 16B chunks; A tile = 512 chunks (threads tid, tid+256),
  // B tile = BN*4 chunks (tid, and tid+256 when BN==128).
  const int c0 = tid, c1 = tid + 256;
  const int ar0 = c0 >> 2, ac0 = (c0 & 3) * 8;
  const int ar1 = c1 >> 2, ac1 = (c1 & 3) * 8;

  for (int k0 = 0; k0 < K; k0 += 32) {
    async_ld16(Ab + (size_t)ar0 * K + k0 + ac0, As + c0 * 8);
    async_ld16(Ab + (size_t)ar1 * K + k0 + ac1, As + c1 * 8);
    async_ld16(Bb + (size_t)ar0 * K + k0 + ac0, Bs + c0 * 8);
    if constexpr (BN == 128)
      async_ld16(Bb + (size_t)ar1 * K + k0 + ac1, Bs + c1 * 8);
    __syncthreads();

    short8 af[4], bfr[MJ];
#pragma unroll
    for (int i = 0; i < 4; ++i)
      af[i] = *(const short8*)(As + (wm + i * 16 + lr) * 32 + quad * 8);
#pragma unroll
    for (int j = 0; j < MJ; ++j)
      bfr[j] = *(const short8*)(Bs + (wn + j * 16 + lr) * 32 + quad * 8);
#pragma unroll
    for (int i = 0; i < 4; ++i)
#pragma unroll
      for (int j = 0; j < MJ; ++j)
        acc[i][j] = __builtin_amdgcn_mfma_f32_16x16x32_bf16(af[i], bfr[j], acc[i][j], 0, 0, 0);
    __syncthreads();
  }

  // C/D layout (verified m89/m91): col = lane&15, row = quad*4 + reg
  if (IS_FC) {
#pragma unroll
    for (int j = 0; j < MJ; ++j) {
      const int nc = n0 + wn + j * 16 + lr;
      const float bv = bias[(size_t)e * N + nc];
#pragma unroll
      for (int i = 0; i < 4; ++i) {
#pragma unroll
        for (int r = 0; r < 4; ++r) {
          const int row = m0 + wm + i * 16 + quad * 4 + r;
          const float v = acc[i][j][r] + bv;
          // gelu_new(v) = v * sigmoid(2c(v + 0.044715 v^3)), c = 0.79788456
          const float u2 = 1.5957691216057308f * (v + 0.044715f * v * v * v);
          const float g = v / (1.0f + __expf(-u2));
          Hout[(size_t)row * N + nc] = __float2bfloat16(g);
        }
      }
    }
  } else {
    const int base_e = bases[e];
    const int cnt = counts[e];
#pragma unroll
    for (int i = 0; i < 4; ++i) {
#pragma unroll
      for (int r = 0; r < 4; ++r) {
        const int row = m0 + wm + i * 16 + quad * 4 + r;
        if (row - base_e < cnt) {   // padded slots: skip (combine never reads them)
          const float w = slot_weight[row];
#pragma unroll
          for (int j = 0; j < MJ; ++j) {
            const int nc = n0 + wn + j * 16 + lr;
            Pout[(size_t)row * N + nc] = (acc[i][j][r] + bias[(size_t)e * N + nc]) * w;
          }
        }
      }
    }
  }
}

extern "C" void kernel_launch(void* const* d_in, const int* in_sizes, int n_in,
                              void* d_out, int out_size, void* d_ws, size_t ws_size,
                              hipStream_t stream) {
  const float* x      = (const float*)d_in[0];
  const float* gate_w = (const float*)d_in[1];
  const float* fc_w   = (const float*)d_in[2];
  const float* fc_b   = (const float*)d_in[3];
  const float* proj_w = (const float*)d_in[4];
  const float* proj_b = (const float*)d_in[5];
  float* out = (float*)d_out;
  float* logits = out + (size_t)T_TOK * D_DIM;

  char* ws = (char*)d_ws;
  __hip_bfloat16* fcT   = (__hip_bfloat16*)(ws);
  float*          P     = (float*)(ws);              // aliases fcT (dead after GEMM1)
  __hip_bfloat16* projT = (__hip_bfloat16*)(ws + 67108864LL);
  __hip_bfloat16* Xg    = (__hip_bfloat16*)(ws + 134217728LL);
  __hip_bfloat16* Hg    = (__hip_bfloat16*)(ws + 153092096LL);
  int* meta = (int*)(ws + 228589568LL);
  int*   counts      = meta;             // 8
  int*   bases       = meta + 8;         // 9
  int*   tk_e        = meta + 20;        // 8192
  int*   tk_pos      = tk_e + 8192;      // 8192
  float* tk_w        = (float*)(tk_pos + 8192);       // 8192
  float* slot_weight = (float*)(tk_w + 8192);         // 9216

  hipMemsetAsync(counts, 0, 8 * sizeof(int), stream);

  // weights: [K][N] fp32 -> [N][K] bf16
  transpose_cast<<<dim3(F_DIM / 64, D_DIM / 64, E_NUM), 256, 0, stream>>>(fc_w, fcT, D_DIM, F_DIM);
  transpose_cast<<<dim3(D_DIM / 64, F_DIM / 64, E_NUM), 256, 0, stream>>>(proj_w, projT, F_DIM, D_DIM);

  router_kernel<<<T_TOK / 4, 256, 0, stream>>>(x, gate_w, logits, counts, tk_e, tk_pos, tk_w);
  prefix_kernel<<<1, 64, 0, stream>>>(counts, bases);
  gather_kernel<<<T_TOK * 2, 256, 0, stream>>>(x, bases, tk_e, tk_pos, tk_w, Xg, slot_weight);

  moe_gemm<F_DIM, D_DIM, 128, true><<<dim3(F_DIM / 128, CAP / 128), 256, 0, stream>>>(
      Xg, fcT, fc_b, counts, bases, Hg, nullptr, nullptr);
  // P overwrites fcT — safe: same stream, GEMM1 (last reader of fcT) precedes it.
  moe_gemm<D_DIM, F_DIM, 64, false><<<dim3(D_DIM / 64, CAP / 128), 256, 0, stream>>>(
      Hg, projT, proj_b, counts, bases, nullptr, slot_weight, P);
  combine_kernel<<<T_TOK, 256, 0, stream>>>(P, bases, tk_e, tk_pos, out);
}

// Round 4
// 657.445 us; speedup vs baseline: 1.1521x; 1.0586x over previous
//
#include <hip/hip_runtime.h>
#include <hip/hip_bf16.h>

// MoE: E=8, K=2, D=1024, F=4096, T=4096 tokens. fp32 in/out, bf16 MFMA inside.
// R3: GEMM1 gets LDS-staged coalesced bf16 epilogue (was 64 scalar 2B stores/thread);
//     GEMM2 gets BK=64 (halved barrier count). Dense P + combine (no atomics) kept.
// ws layout (bytes):
//   [0,          64MB)  fcT   bf16 [8][4096][1024]  -- ALIASED by P after GEMM1
//   [0,       37.75MB)  P     fp32 [9216][1024]      (GEMM2 dense output; fcT dead by then)
//   [64MB,      128MB)  projT bf16 [8][1024][4096]
//   [128MB, +18.0MB )   Xg    bf16 [9216][1024]
//   [146MB, +75.5MB )   Hg    bf16 [9216][4096]
//   [~218MB, meta]      counts[8], bases[9], tk_e/tk_pos/tk_w[8192], slot_weight[9216]

#define T_TOK 4096
#define D_DIM 1024
#define F_DIM 4096
#define E_NUM 8
#define CAP   9216   // 72 tiles * 128

typedef short short8 __attribute__((ext_vector_type(8)));
typedef float f32x4  __attribute__((ext_vector_type(4)));

__device__ __forceinline__ void async_ld16(const void* g, void* l) {
  __builtin_amdgcn_global_load_lds(
      (const __attribute__((address_space(1))) char*)g,
      (__attribute__((address_space(3))) char*)l,
      16, 0, 0);
}

__device__ __forceinline__ float gelu_new(float v) {
  // v * sigmoid(2c(v + 0.044715 v^3)), c = 0.79788456
  const float u2 = 1.5957691216057308f * (v + 0.044715f * v * v * v);
  return v / (1.0f + __expf(-u2));
}

// ---------------- transpose + fp32->bf16 cast:  in [E][R][C] -> out [E][C][R]
__global__ void transpose_cast(const float* __restrict__ in, __hip_bfloat16* __restrict__ out,
                               int R, int C) {
  __shared__ float t[64][65];
  const int ex = blockIdx.z;
  in  += (size_t)ex * R * C;
  out += (size_t)ex * R * C;
  const int r0 = blockIdx.y * 64, c0 = blockIdx.x * 64;
  const int tx = threadIdx.x & 15;        // 16 x float4 across 64 cols
  const int ty = threadIdx.x >> 4;        // 16 rows per pass
#pragma unroll
  for (int i = 0; i < 4; ++i) {
    const int r = ty + i * 16;
    const float4 v = *(const float4*)(in + (size_t)(r0 + r) * C + c0 + tx * 4);
    t[r][tx * 4 + 0] = v.x; t[r][tx * 4 + 1] = v.y;
    t[r][tx * 4 + 2] = v.z; t[r][tx * 4 + 3] = v.w;
  }
  __syncthreads();
#pragma unroll
  for (int i = 0; i < 4; ++i) {
    const int c = ty + i * 16;            // col in tile -> output row
    union { __hip_bfloat16 h[4]; ushort4 u; } pk;
#pragma unroll
    for (int k = 0; k < 4; ++k) pk.h[k] = __float2bfloat16(t[tx * 4 + k][c]);
    *(ushort4*)(out + (size_t)(c0 + c) * R + r0 + tx * 4) = pk.u;
  }
}

// ---------------- router: logits (fp32 out), softmax, top-2, slot assignment
__global__ void router_kernel(const float* __restrict__ x, const float* __restrict__ gw,
                              float* __restrict__ logits, int* __restrict__ counts,
                              int* __restrict__ tk_e, int* __restrict__ tk_pos,
                              float* __restrict__ tk_w) {
  const int lane = threadIdx.x & 63;
  const int t = blockIdx.x * 4 + (threadIdx.x >> 6);
  const float* xr = x + (size_t)t * D_DIM;
  float a[8] = {0.f, 0.f, 0.f, 0.f, 0.f, 0.f, 0.f, 0.f};
  for (int it = 0; it < D_DIM / 64; ++it) {
    const int d = lane + it * 64;
    const float xv = xr[d];
    const float4 g0 = *(const float4*)(gw + d * 8);
    const float4 g1 = *(const float4*)(gw + d * 8 + 4);
    a[0] += xv * g0.x; a[1] += xv * g0.y; a[2] += xv * g0.z; a[3] += xv * g0.w;
    a[4] += xv * g1.x; a[5] += xv * g1.y; a[6] += xv * g1.z; a[7] += xv * g1.w;
  }
#pragma unroll
  for (int off = 32; off > 0; off >>= 1)
#pragma unroll
    for (int e = 0; e < 8; ++e) a[e] += __shfl_down(a[e], off);
  if (lane == 0) {
    float mx = a[0];
#pragma unroll
    for (int e = 1; e < 8; ++e) mx = fmaxf(mx, a[e]);
    float p[8];
#pragma unroll
    for (int e = 0; e < 8; ++e) p[e] = __expf(a[e] - mx);
    int i1 = 0;
#pragma unroll
    for (int e = 1; e < 8; ++e) if (p[e] > p[i1]) i1 = e;   // strict >: lowest index on tie (lax.top_k)
    int i2 = (i1 == 0) ? 1 : 0;
#pragma unroll
    for (int e = 0; e < 8; ++e) if (e != i1 && p[e] > p[i2]) i2 = e;
    const float inv = 1.f / (p[i1] + p[i2]);
#pragma unroll
    for (int e = 0; e < 8; ++e) logits[(size_t)t * 8 + e] = a[e];
    const int p1 = atomicAdd(counts + i1, 1);
    const int p2 = atomicAdd(counts + i2, 1);
    tk_e[t * 2]     = i1; tk_pos[t * 2]     = p1; tk_w[t * 2]     = p[i1] * inv;
    tk_e[t * 2 + 1] = i2; tk_pos[t * 2 + 1] = p2; tk_w[t * 2 + 1] = p[i2] * inv;
  }
}

// ---------------- bases: 128-aligned prefix sum so GEMM tiles never straddle experts
__global__ void prefix_kernel(const int* __restrict__ counts, int* __restrict__ bases) {
  if (threadIdx.x == 0 && blockIdx.x == 0) {
    int b = 0;
    for (int e = 0; e < 8; ++e) { bases[e] = b; b += (counts[e] + 127) & ~127; }
    bases[8] = b;
  }
}

// ---------------- gather token rows into Xg (bf16), fill slot weights
__global__ void gather_kernel(const float* __restrict__ x, const int* __restrict__ bases,
                              const int* __restrict__ tk_e, const int* __restrict__ tk_pos,
                              const float* __restrict__ tk_w,
                              __hip_bfloat16* __restrict__ Xg,
                              float* __restrict__ slot_weight) {
  const int b = blockIdx.x;        // (token, k) pair
  const int t = b >> 1;
  const int slot = bases[tk_e[b]] + tk_pos[b];
  if (threadIdx.x == 0) slot_weight[slot] = tk_w[b];
  const float4 v = ((const float4*)(x + (size_t)t * D_DIM))[threadIdx.x];
  union { __hip_bfloat16 h[4]; ushort4 u; } pk;
  pk.h[0] = __float2bfloat16(v.x);
  pk.h[1] = __float2bfloat16(v.y);
  pk.h[2] = __float2bfloat16(v.z);
  pk.h[3] = __float2bfloat16(v.w);
  ((ushort4*)(Xg + (size_t)slot * D_DIM))[threadIdx.x] = pk.u;
}

// ---------------- combine: out[t] = P[slot1(t)] + P[slot2(t)]
__global__ void combine_kernel(const float* __restrict__ P, const int* __restrict__ bases,
                               const int* __restrict__ tk_e, const int* __restrict__ tk_pos,
                               float* __restrict__ out) {
  const int t = blockIdx.x;
  const int s1 = bases[tk_e[2 * t]]     + tk_pos[2 * t];
  const int s2 = bases[tk_e[2 * t + 1]] + tk_pos[2 * t + 1];
  const int d = threadIdx.x * 4;
  const float4 a = *(const float4*)(P + (size_t)s1 * D_DIM + d);
  const float4 b = *(const float4*)(P + (size_t)s2 * D_DIM + d);
  float4 o; o.x = a.x + b.x; o.y = a.y + b.y; o.z = a.z + b.z; o.w = a.w + b.w;
  *(float4*)(out + (size_t)t * D_DIM + d) = o;
}

// ---------------- GEMM1 (fc): 128x128 tile, BK=32. Hg = gelu_new(Xg@fcT + fc_b), bf16.
// Epilogue round-trips acc through LDS -> coalesced 16B stores.
__global__ __launch_bounds__(256, 2) void gemm_fc(
    const __hip_bfloat16* __restrict__ A, const __hip_bfloat16* __restrict__ Bt,
    const float* __restrict__ bias, const int* __restrict__ bases,
    __hip_bfloat16* __restrict__ Hout) {
  constexpr int N = F_DIM, K = D_DIM;
  __shared__ __align__(16) char smem[17408];   // max(As+Bs=16K, EP=32*132*4=16.5K)
  __hip_bfloat16* As = (__hip_bfloat16*)smem;
  __hip_bfloat16* Bs = As + 128 * 32;
  float* EP = (float*)smem;

  const int m0 = blockIdx.y * 128;
  if (m0 >= bases[8]) return;
  int e = 0;
#pragma unroll
  for (int i = 1; i < 8; ++i) e = (m0 >= bases[i]) ? i : e;
  const int n0 = blockIdx.x * 128;

  const __hip_bfloat16* Ab = A + (size_t)m0 * K;
  const __hip_bfloat16* Bb = Bt + ((size_t)e * N + n0) * K;

  const int tid = threadIdx.x;
  const int lane = tid & 63;
  const int wave = tid >> 6;
  const int wm = (wave >> 1) * 64;
  const int wn = (wave & 1) * 64;
  const int lr = lane & 15;
  const int quad = lane >> 4;

  f32x4 acc[4][4] = {};

  const int c0 = tid, c1 = tid + 256;
  const int ar0 = c0 >> 2, ac0 = (c0 & 3) * 8;
  const int ar1 = c1 >> 2, ac1 = (c1 & 3) * 8;

  for (int k0 = 0; k0 < K; k0 += 32) {
    async_ld16(Ab + (size_t)ar0 * K + k0 + ac0, As + c0 * 8);
    async_ld16(Ab + (size_t)ar1 * K + k0 + ac1, As + c1 * 8);
    async_ld16(Bb + (size_t)ar0 * K + k0 + ac0, Bs + c0 * 8);
    async_ld16(Bb + (size_t)ar1 * K + k0 + ac1, Bs + c1 * 8);
    __syncthreads();

    short8 af[4], bfr[4];
#pragma unroll
    for (int i = 0; i < 4; ++i)
      af[i] = *(const short8*)(As + (wm + i * 16 + lr) * 32 + quad * 8);
#pragma unroll
    for (int j = 0; j < 4; ++j)
      bfr[j] = *(const short8*)(Bs + (wn + j * 16 + lr) * 32 + quad * 8);
#pragma unroll
    for (int i = 0; i < 4; ++i)
#pragma unroll
      for (int j = 0; j < 4; ++j)
        acc[i][j] = __builtin_amdgcn_mfma_f32_16x16x32_bf16(af[i], bfr[j], acc[i][j], 0, 0, 0);
    __syncthreads();
  }

  // Epilogue: 4 passes of 32 rows. C/D layout: col=lane&15, row=quad*4+reg.
  const int pbase = wm >> 5;                    // 0 for waves 0/1, 2 for waves 2/3
  const int row = tid >> 3;                     // read-back: 8 threads per row
  const int col0 = (tid & 7) * 16;
#pragma unroll
  for (int p = 0; p < 4; ++p) {
    const int pl = p - pbase;
    if (pl == 0 || pl == 1) {
#pragma unroll
      for (int ii = 0; ii < 2; ++ii) {
        const int i = 2 * pl + ii;
#pragma unroll
        for (int j = 0; j < 4; ++j)
#pragma unroll
          for (int r = 0; r < 4; ++r)
            EP[(ii * 16 + quad * 4 + r) * 132 + wn + j * 16 + lr] = acc[i][j][r];
      }
    }
    __syncthreads();
    union { __hip_bfloat16 h[16]; short8 s[2]; } pk;
#pragma unroll
    for (int c4 = 0; c4 < 4; ++c4) {
      const f32x4 v = *(const f32x4*)(EP + row * 132 + col0 + c4 * 4);
#pragma unroll
      for (int k = 0; k < 4; ++k) pk.h[c4 * 4 + k] = __float2bfloat16(gelu_new(v[k]));
    }
    short8* dst = (short8*)(Hout + (size_t)(m0 + p * 32 + row) * N + n0 + col0);
    dst[0] = pk.s[0];
    dst[1] = pk.s[1];
    __syncthreads();
  }
}

// ---------------- GEMM2 (proj): 128x64 tile, BK=64 (halved barrier count).
// P[row][:] = (Hg@projT + proj_b) * slot_weight[row], dense fp32; padded rows skipped.
__global__ __launch_bounds__(256, 2) void gemm_proj(
    const __hip_bfloat16* __restrict__ A, const __hip_bfloat16* __restrict__ Bt,
    const float* __restrict__ bias, const int* __restrict__ counts,
    const int* __restrict__ bases, const float* __restrict__ slot_weight,
    float* __restrict__ Pout) {
  constexpr int N = D_DIM, K = F_DIM;
  __shared__ __align__(16) __hip_bfloat16 As[128 * 64];   // 16 KB
  __shared__ __align__(16) __hip_bfloat16 Bs[64 * 64];    //  8 KB

  const int m0 = blockIdx.y * 128;
  if (m0 >= bases[8]) return;
  int e = 0;
#pragma unroll
  for (int i = 1; i < 8; ++i) e = (m0 >= bases[i]) ? i : e;
  const int n0 = blockIdx.x * 64;

  const __hip_bfloat16* Ab = A + (size_t)m0 * K;
  const __hip_bfloat16* Bb = Bt + ((size_t)e * N + n0) * K;

  const int tid = threadIdx.x;
  const int lane = tid & 63;
  const int wave = tid >> 6;
  const int wm = (wave >> 1) * 64;
  const int wn = (wave & 1) * 32;
  const int lr = lane & 15;
  const int quad = lane >> 4;

  f32x4 acc[4][2] = {};

  // A tile: 128 rows x 64 k = 1024 chunks (4/thread); B tile: 64 x 64 = 512 chunks (2/thread)
  for (int k0 = 0; k0 < K; k0 += 64) {
#pragma unroll
    for (int q = 0; q < 4; ++q) {
      const int c = tid + q * 256;
      async_ld16(Ab + (size_t)(c >> 3) * K + k0 + (c & 7) * 8, As + c * 8);
    }
#pragma unroll
    for (int q = 0; q < 2; ++q) {
      const int c = tid + q * 256;
      async_ld16(Bb + (size_t)(c >> 3) * K + k0 + (c & 7) * 8, Bs + c * 8);
    }
    __syncthreads();

#pragma unroll
    for (int s = 0; s < 2; ++s) {
      short8 af[4], bfr[2];
#pragma unroll
      for (int i = 0; i < 4; ++i)
        af[i] = *(const short8*)(As + (wm + i * 16 + lr) * 64 + s * 32 + quad * 8);
#pragma unroll
      for (int j = 0; j < 2; ++j)
        bfr[j] = *(const short8*)(Bs + (wn + j * 16 + lr) * 64 + s * 32 + quad * 8);
#pragma unroll
      for (int i = 0; i < 4; ++i)
#pragma unroll
        for (int j = 0; j < 2; ++j)
          acc[i][j] = __builtin_amdgcn_mfma_f32_16x16x32_bf16(af[i], bfr[j], acc[i][j], 0, 0, 0);
    }
    __syncthreads();
  }

  const int base_e = bases[e];
  const int cnt = counts[e];
#pragma unroll
  for (int i = 0; i < 4; ++i) {
#pragma unroll
    for (int r = 0; r < 4; ++r) {
      const int row = m0 + wm + i * 16 + quad * 4 + r;
      if (row - base_e < cnt) {   // padded slots: skip (combine never reads them)
        const float w = slot_weight[row];
#pragma unroll
        for (int j = 0; j < 2; ++j) {
          const int nc = n0 + wn + j * 16 + lr;
          Pout[(size_t)row * N + nc] = (acc[i][j][r] + bias[(size_t)e * N + nc]) * w;
        }
      }
    }
  }
}

extern "C" void kernel_launch(void* const* d_in, const int* in_sizes, int n_in,
                              void* d_out, int out_size, void* d_ws, size_t ws_size,
                              hipStream_t stream) {
  const float* x      = (const float*)d_in[0];
  const float* gate_w = (const float*)d_in[1];
  const float* fc_w   = (const float*)d_in[2];
  const float* fc_b   = (const float*)d_in[3];
  const float* proj_w = (const float*)d_in[4];
  const float* proj_b = (const float*)d_in[5];
  float* out = (float*)d_out;
  float* logits = out + (size_t)T_TOK * D_DIM;

  char* ws = (char*)d_ws;
  __hip_bfloat16* fcT   = (__hip_bfloat16*)(ws);
  float*          P     = (float*)(ws);              // aliases fcT (dead after GEMM1)
  __hip_bfloat16* projT = (__hip_bfloat16*)(ws + 67108864LL);
  __hip_bfloat16* Xg    = (__hip_bfloat16*)(ws + 134217728LL);
  __hip_bfloat16* Hg    = (__hip_bfloat16*)(ws + 153092096LL);
  int* meta = (int*)(ws + 228589568LL);
  int*   counts      = meta;             // 8
  int*   bases       = meta + 8;         // 9
  int*   tk_e        = meta + 20;        // 8192
  int*   tk_pos      = tk_e + 8192;      // 8192
  float* tk_w        = (float*)(tk_pos + 8192);       // 8192
  float* slot_weight = (float*)(tk_w + 8192);         // 9216

  hipMemsetAsync(counts, 0, 8 * sizeof(int), stream);

  // weights: [K][N] fp32 -> [N][K] bf16
  transpose_cast<<<dim3(F_DIM / 64, D_DIM / 64, E_NUM), 256, 0, stream>>>(fc_w, fcT, D_DIM, F_DIM);
  transpose_cast<<<dim3(D_DIM / 64, F_DIM / 64, E_NUM), 256, 0, stream>>>(proj_w, projT, F_DIM, D_DIM);

  router_kernel<<<T_TOK / 4, 256, 0, stream>>>(x, gate_w, logits, counts, tk_e, tk_pos, tk_w);
  prefix_kernel<<<1, 64, 0, stream>>>(counts, bases);
  gather_kernel<<<T_TOK * 2, 256, 0, stream>>>(x, bases, tk_e, tk_pos, tk_w, Xg, slot_weight);

  gemm_fc<<<dim3(F_DIM / 128, CAP / 128), 256, 0, stream>>>(Xg, fcT, fc_b, bases, Hg);
  // P overwrites fcT — safe: same stream, GEMM1 (last reader of fcT) precedes it.
  gemm_proj<<<dim3(D_DIM / 64, CAP / 128), 256, 0, stream>>>(Hg, projT, proj_b, counts, bases,
                                                             slot_weight, P);
  combine_kernel<<<T_TOK, 256, 0, stream>>>(P, bases, tk_e, tk_pos, out);
}